// Round 15
// baseline (84.829 us; speedup 1.0000x reference)
//
#include <hip/hip_runtime.h>
#include <stdint.h>

typedef float f32x4 __attribute__((ext_vector_type(4)));
typedef uint32_t u32x4 __attribute__((ext_vector_type(4)));
typedef short s16x8 __attribute__((ext_vector_type(8)));

#define BB   8
#define NN   2048
#define FIN  128
#define FOUT 64

__device__ __forceinline__ uint32_t cvt_pk_bf16(float lo, float hi) {
  uint32_t r;
  asm("v_cvt_pk_bf16_f32 %0, %1, %2" : "=v"(r) : "v"(lo), "v"(hi));
  return r;
}

__device__ __forceinline__ s16x8 mk_s16x8(uint32_t a, uint32_t b, uint32_t c, uint32_t d) {
  union { uint32_t u[4]; s16x8 v; } x;
  x.u[0] = a; x.u[1] = b; x.u[2] = c; x.u[3] = d;
  return x.v;
}

// ---------------------------------------------------------------------------
// k01: fused. ALL 4096 blocks do a 4-row adj->bitmask slice (coalesced).
// Blocks with (blockIdx&15)==8 (256, SPREAD through dispatch order) also run
// the k1 hidden/s1/s2 body -- extra work back-fills instead of tailing.
// ---------------------------------------------------------------------------
__global__ void k01(const float* __restrict__ adj, uint32_t* __restrict__ mask,
                    const float* __restrict__ h, const float* __restrict__ W,
                    const float* __restrict__ attw, ushort* __restrict__ hidT,
                    float* __restrict__ s1, float* __restrict__ s2) {
  __shared__ uint8_t nib[4][512];
  __shared__ ushort wlds[FOUT * 136];

  const int tid  = threadIdx.x;
  const int lane = tid & 63, wid = tid >> 6;

  // ---- mask slice (all blocks) ----
  {
    const int row = blockIdx.x * 4 + wid;
    const float* base = adj + (size_t)row * NN;
    #pragma unroll
    for (int t = 0; t < 8; ++t) {
      f32x4 v = *(const f32x4*)(base + 256 * t + 4 * lane);
      uint32_t n = (v[0] > 0.f ? 1u : 0u) | (v[1] > 0.f ? 2u : 0u) |
                   (v[2] > 0.f ? 4u : 0u) | (v[3] > 0.f ? 8u : 0u);
      nib[wid][t * 64 + lane] = (uint8_t)n;
    }
    __syncthreads();
    uint64_t x = *(const uint64_t*)(&nib[wid][8 * lane]);
    uint64_t v = (x | (x >> 4))  & 0x00FF00FF00FF00FFull;
    v          = (v | (v >> 8))  & 0x0000FFFF0000FFFFull;
    v          = (v | (v >> 16));
    mask[(size_t)row * 64 + lane] = (uint32_t)v;
  }

  // ---- k1 body (spread blocks only) ----
  if ((blockIdx.x & 15) == 8) {
    const int kb = blockIdx.x >> 4;            // 0..255
    for (int idx = tid; idx < FIN * FOUT; idx += 256) {
      int k = idx >> 6, c = idx & 63;
      wlds[c * 136 + k] = (ushort)(cvt_pk_bf16(W[idx], 0.f) & 0xffffu);
    }
    __syncthreads();

    const int bid = ((kb & 7) << 5) | (kb >> 3);
    const int q = lane & 15, g = lane >> 4;
    const int wrow0 = bid * 64 + wid * 16;
    const int b  = wrow0 >> 11;
    const int n0 = wrow0 & (NN - 1);

    const float* hrow = h + (size_t)(wrow0 + q) * FIN + 8 * g;

    f32x4 acc[4];
    #pragma unroll
    for (int nt = 0; nt < 4; ++nt) acc[nt] = {0.f, 0.f, 0.f, 0.f};

    #pragma unroll
    for (int kk = 0; kk < 4; ++kk) {
      f32x4 h0 = *(const f32x4*)(hrow + 32 * kk);
      f32x4 h1 = *(const f32x4*)(hrow + 32 * kk + 4);
      s16x8 A = mk_s16x8(cvt_pk_bf16(h0[0], h0[1]), cvt_pk_bf16(h0[2], h0[3]),
                         cvt_pk_bf16(h1[0], h1[1]), cvt_pk_bf16(h1[2], h1[3]));
      #pragma unroll
      for (int nt = 0; nt < 4; ++nt) {
        s16x8 Bf = *(const s16x8*)(&wlds[(nt * 16 + q) * 136 + 32 * kk + 8 * g]);
        acc[nt] = __builtin_amdgcn_mfma_f32_16x16x32_bf16(A, Bf, acc[nt], 0, 0, 0);
      }
    }

    float a1v[4], a2v[4];
    #pragma unroll
    for (int nt = 0; nt < 4; ++nt) {
      a1v[nt] = attw[nt * 16 + q];
      a2v[nt] = attw[64 + nt * 16 + q];
    }
    float p1[4], p2[4];
    #pragma unroll
    for (int r = 0; r < 4; ++r) {
      float v1 = 0.f, v2 = 0.f;
      #pragma unroll
      for (int nt = 0; nt < 4; ++nt) { v1 += acc[nt][r] * a1v[nt]; v2 += acc[nt][r] * a2v[nt]; }
      #pragma unroll
      for (int m = 1; m < 16; m <<= 1) { v1 += __shfl_xor(v1, m, 64); v2 += __shfl_xor(v2, m, 64); }
      p1[r] = v1; p2[r] = v2;
    }
    if (q < 4) {
      int gr = wrow0 + 4 * g + q;
      float v1 = (q == 0) ? p1[0] : (q == 1) ? p1[1] : (q == 2) ? p1[2] : p1[3];
      float v2 = (q == 0) ? p2[0] : (q == 1) ? p2[1] : (q == 2) ? p2[2] : p2[3];
      s1[gr] = v1; s2[gr] = v2;
    }

    #pragma unroll
    for (int nt = 0; nt < 4; ++nt) {
      uint32_t lo = cvt_pk_bf16(acc[nt][0], acc[nt][1]);
      uint32_t hi = cvt_pk_bf16(acc[nt][2], acc[nt][3]);
      *(uint2*)(hidT + ((size_t)b * FOUT + nt * 16 + q) * NN + n0 + 4 * g) = make_uint2(lo, hi);
    }
  }
}

// ---------------------------------------------------------------------------
// k2 v6: GEMM-style + DOUBLE-BUFFERED staging, 1 barrier/chunk.
// grid 1024 x 512 thr. Block = 64 i-rows x 512-j window, 4 chunks of 128 j.
// Chunk c+1's global loads issue before chunk c's compute; ds_write goes to
// the other buffer (no race); single barrier per chunk.
// part[] combine aliases Hb[0] (dead after the k-loop).
// ---------------------------------------------------------------------------
__global__ void k2_attn(
    const uint32_t* __restrict__ mask, const ushort* __restrict__ hidT,
    const float* __restrict__ s1, const float* __restrict__ s2,
    float* __restrict__ parts) {
  __shared__ __align__(16) char Hb[2][16384];
  __shared__ float s2l[512];
  __shared__ float partl[4][16];

  const int tid = threadIdx.x;
  // XCD swizzle: 1024 blocks, XCD x <- batch x
  const int sb  = ((blockIdx.x & 7) << 7) | (blockIdx.x >> 3);
  const int b   = sb >> 7;
  const int rem = sb & 127;
  const int ib  = rem >> 2;           // i-block 0..31
  const int jq  = rem & 3;            // j-window 0..3
  const int i0  = ib << 6;
  const int jbase = jq << 9;          // 512-j window start

  if (tid < 512) s2l[tid] = s2[b * NN + jbase + tid];

  const int lane = tid & 63, wid = tid >> 6;
  const int q = lane & 15, g = lane >> 4;
  const int r16 = wid & 3;            // row-group
  const int jp  = wid >> 2;           // j-half within chunk
  const int row = i0 + r16 * 16 + q;
  const float s1r = s1[b * NN + row];
  const uint32_t* mrow = mask + (size_t)(b * NN + row) * 64 + jq * 16 + jp * 2;

  const ushort* hsrc = hidT + (size_t)b * FOUT * NN + jbase;
  const int sf = tid >> 4;            // staging f-row 0..31 (+32 second half)
  const int jslot = tid & 15;         // staging 16B slot
  const int swz = (q & 7) << 4;
  const int gsh = g << 3;

  f32x4 acc0 = {0,0,0,0}, acc1 = {0,0,0,0}, acc2 = {0,0,0,0}, acc3 = {0,0,0,0};
  float lsum = 0.f;

  u32x4 v0, v1;
  #define LOADC(cc) do {                                                      \
    const ushort* hp_ = hsrc + (size_t)sf * NN + (cc) * 128 + jslot * 8;      \
    v0 = *(const u32x4*)hp_;                                                  \
    v1 = *(const u32x4*)(hp_ + (size_t)32 * NN);                              \
  } while (0)

  #define DSWC(bb) do {                                                       \
    char* db = Hb[bb];                                                        \
    *(u32x4*)(db + (sf << 8) + ((jslot << 4) ^ ((sf & 7) << 4))) = v0;        \
    *(u32x4*)(db + ((sf + 32) << 8) + ((jslot << 4) ^ ((sf & 7) << 4))) = v1; \
  } while (0)

  // prologue: stage chunk 0
  LOADC(0);
  DSWC(0);
  __syncthreads();

  #pragma unroll
  for (int c = 0; c < 4; ++c) {
    if (c < 3) LOADC(c + 1);           // issue early; lands during compute

    const char* tb = Hb[c & 1];
    #pragma unroll
    for (int s = 0; s < 2; ++s) {
      const int jl = jp * 64 + s * 32 + 8 * g;     // chunk-local 0..127
      const uint32_t mb = (mrow[c * 4 + s] >> gsh) & 0xffu;
      f32x4 ct0 = *(const f32x4*)(s2l + c * 128 + jl);
      f32x4 ct1 = *(const f32x4*)(s2l + c * 128 + jl + 4);
      const int jb = (jl << 1);                    // byte in 256B row
      u32x4 cb0 = *(const u32x4*)(tb + (((0 * 16 + q) << 8) + (jb ^ swz)));
      u32x4 cb1 = *(const u32x4*)(tb + (((1 * 16 + q) << 8) + (jb ^ swz)));
      u32x4 cb2 = *(const u32x4*)(tb + (((2 * 16 + q) << 8) + (jb ^ swz)));
      u32x4 cb3 = *(const u32x4*)(tb + (((3 * 16 + q) << 8) + (jb ^ swz)));

      float e0 = s1r + ct0[0], e1 = s1r + ct0[1], e2 = s1r + ct0[2], e3 = s1r + ct0[3];
      float e4 = s1r + ct1[0], e5 = s1r + ct1[1], e6 = s1r + ct1[2], e7 = s1r + ct1[3];
      float p0 = (mb &   1u) ? __expf(fmaxf(e0, 0.2f * e0)) : 0.f;
      float p1 = (mb &   2u) ? __expf(fmaxf(e1, 0.2f * e1)) : 0.f;
      float p2 = (mb &   4u) ? __expf(fmaxf(e2, 0.2f * e2)) : 0.f;
      float p3 = (mb &   8u) ? __expf(fmaxf(e3, 0.2f * e3)) : 0.f;
      float p4 = (mb &  16u) ? __expf(fmaxf(e4, 0.2f * e4)) : 0.f;
      float p5 = (mb &  32u) ? __expf(fmaxf(e5, 0.2f * e5)) : 0.f;
      float p6 = (mb &  64u) ? __expf(fmaxf(e6, 0.2f * e6)) : 0.f;
      float p7 = (mb & 128u) ? __expf(fmaxf(e7, 0.2f * e7)) : 0.f;
      lsum += ((p0 + p1) + (p2 + p3)) + ((p4 + p5) + (p6 + p7));

      s16x8 A = mk_s16x8(cvt_pk_bf16(p0, p1), cvt_pk_bf16(p2, p3),
                         cvt_pk_bf16(p4, p5), cvt_pk_bf16(p6, p7));
      union { u32x4 u; s16x8 v; } w0, w1, w2, w3;
      w0.u = cb0; w1.u = cb1; w2.u = cb2; w3.u = cb3;
      acc0 = __builtin_amdgcn_mfma_f32_16x16x32_bf16(A, w0.v, acc0, 0, 0, 0);
      acc1 = __builtin_amdgcn_mfma_f32_16x16x32_bf16(A, w1.v, acc1, 0, 0, 0);
      acc2 = __builtin_amdgcn_mfma_f32_16x16x32_bf16(A, w2.v, acc2, 0, 0, 0);
      acc3 = __builtin_amdgcn_mfma_f32_16x16x32_bf16(A, w3.v, acc3, 0, 0, 0);
    }

    if (c < 3) DSWC((c + 1) & 1);      // write-late into the other buffer
    __syncthreads();
  }

  // reduce lsum over g-groups -> all lanes hold row-q sum (this wave's j-part)
  lsum += __shfl_xor(lsum, 16, 64);
  lsum += __shfl_xor(lsum, 32, 64);

  // combine j-half pairs (wid and wid+4 share rows); part aliases Hb[0]
  float* part = (float*)Hb[0];   // [4][16][64]
  if (wid >= 4) {
    if (lane < 16) partl[wid - 4][lane] = lsum;
    #pragma unroll
    for (int r = 0; r < 4; ++r) {
      part[((wid - 4) * 16 + 4 * g + r) * 64 +  0 + q] = acc0[r];
      part[((wid - 4) * 16 + 4 * g + r) * 64 + 16 + q] = acc1[r];
      part[((wid - 4) * 16 + 4 * g + r) * 64 + 32 + q] = acc2[r];
      part[((wid - 4) * 16 + 4 * g + r) * 64 + 48 + q] = acc3[r];
    }
  }
  __syncthreads();
  if (wid < 4) {
    lsum += partl[wid][q];
    #pragma unroll
    for (int r = 0; r < 4; ++r) {
      acc0[r] += part[(wid * 16 + 4 * g + r) * 64 +  0 + q];
      acc1[r] += part[(wid * 16 + 4 * g + r) * 64 + 16 + q];
      acc2[r] += part[(wid * 16 + 4 * g + r) * 64 + 32 + q];
      acc3[r] += part[(wid * 16 + 4 * g + r) * 64 + 48 + q];
    }
    float* po = parts + ((size_t)(b * 32 + ib) * 4 + jq) * 4160;
    #pragma unroll
    for (int r = 0; r < 4; ++r) {
      po[(r16 * 16 + 4 * g + r) * 64 +  0 + q] = acc0[r];
      po[(r16 * 16 + 4 * g + r) * 64 + 16 + q] = acc1[r];
      po[(r16 * 16 + 4 * g + r) * 64 + 32 + q] = acc2[r];
      po[(r16 * 16 + 4 * g + r) * 64 + 48 + q] = acc3[r];
    }
    if (lane < 16) po[4096 + r16 * 16 + q] = lsum;
  }
}

// ---------------------------------------------------------------------------
// k3: combine 4 j-window partials, normalize, ELU, write out.
// grid 256 x 256 thr; one 64x64 i-tile per block.
// ---------------------------------------------------------------------------
__global__ void k3_combine(const float* __restrict__ parts, float* __restrict__ out) {
  __shared__ float lrow[64];
  const int tid = threadIdx.x;
  const int sb  = ((blockIdx.x & 7) << 5) | (blockIdx.x >> 3);
  const int b   = sb >> 5;
  const int ib  = sb & 31;
  const float* p0 = parts + (size_t)(b * 32 + ib) * 4 * 4160;

  if (tid < 64)
    lrow[tid] = (p0[4096 + tid] + p0[4160 + 4096 + tid]) +
                (p0[8320 + 4096 + tid] + p0[12480 + 4096 + tid]);
  __syncthreads();

  #pragma unroll
  for (int k = 0; k < 16; ++k) {
    const int idx = k * 256 + tid;
    const int row = idx >> 6, col = idx & 63;
    float v = (p0[idx] + p0[4160 + idx]) + (p0[8320 + idx] + p0[12480 + idx]);
    float hp = v / lrow[row];
    out[(size_t)(b * NN + ib * 64 + row) * 64 + col] = (hp > 0.f) ? hp : expm1f(hp);
  }
}

extern "C" void kernel_launch(void* const* d_in, const int* in_sizes, int n_in,
                              void* d_out, int out_size, void* d_ws, size_t ws_size,
                              hipStream_t stream) {
  const float* h    = (const float*)d_in[0];
  const float* adj  = (const float*)d_in[1];
  const float* W    = (const float*)d_in[2];
  const float* attw = (const float*)d_in[3];
  float* out = (float*)d_out;

  char* ws = (char*)d_ws;
  ushort*   hidT  = (ushort*)ws;                                // 2 MB
  float*    s1    = (float*)(ws + (2u << 20));                  // 64 KB
  float*    s2    = (float*)(ws + (2u << 20) + (64u << 10));    // 64 KB
  uint32_t* mask  = (uint32_t*)(ws + (4u << 20));               // 4 MB
  float*    parts = (float*)(ws + (8u << 20));                  // 17 MB

  hipLaunchKernelGGL(k01, dim3(4096), dim3(256), 0, stream,
                     adj, mask, h, W, attw, hidT, s1, s2);
  hipLaunchKernelGGL(k2_attn, dim3(1024), dim3(512), 0, stream,
                     mask, hidT, s1, s2, parts);
  hipLaunchKernelGGL(k3_combine, dim3(256), dim3(256), 0, stream, parts, out);
}

// Round 16
// 59.888 us; speedup vs baseline: 1.4165x; 1.4165x over previous
//
#include <hip/hip_runtime.h>
#include <stdint.h>

typedef float f32x4 __attribute__((ext_vector_type(4)));
typedef uint32_t u32x4 __attribute__((ext_vector_type(4)));
typedef short s16x8 __attribute__((ext_vector_type(8)));

#define BB   8
#define NN   2048
#define FIN  128
#define FOUT 64

__device__ __forceinline__ uint32_t cvt_pk_bf16(float lo, float hi) {
  uint32_t r;
  asm("v_cvt_pk_bf16_f32 %0, %1, %2" : "=v"(r) : "v"(lo), "v"(hi));
  return r;
}

__device__ __forceinline__ s16x8 mk_s16x8(uint32_t a, uint32_t b, uint32_t c, uint32_t d) {
  union { uint32_t u[4]; s16x8 v; } x;
  x.u[0] = a; x.u[1] = b; x.u[2] = c; x.u[3] = d;
  return x.v;
}

// ---------------------------------------------------------------------------
// k01 (R14 verbatim): ALL 4096 blocks do a 4-row adj->bitmask slice.
// Blocks < 256 also run the k1 hidden/s1/s2 body.  NOTE: predicate must NOT
// alias XCD round-robin (blockIdx%8) -- R15's (&15)==8 put all k1 work on
// XCD 0 and serialized it.  blockIdx<256 spreads across all 8 XCDs.
// ---------------------------------------------------------------------------
__global__ void k01(const float* __restrict__ adj, uint32_t* __restrict__ mask,
                    const float* __restrict__ h, const float* __restrict__ W,
                    const float* __restrict__ attw, ushort* __restrict__ hidT,
                    float* __restrict__ s1, float* __restrict__ s2) {
  __shared__ uint8_t nib[4][512];
  __shared__ ushort wlds[FOUT * 136];

  const int tid  = threadIdx.x;
  const int lane = tid & 63, wid = tid >> 6;

  // ---- mask slice (all blocks) ----
  {
    const int row = blockIdx.x * 4 + wid;
    const float* base = adj + (size_t)row * NN;
    #pragma unroll
    for (int t = 0; t < 8; ++t) {
      f32x4 v = *(const f32x4*)(base + 256 * t + 4 * lane);
      uint32_t n = (v[0] > 0.f ? 1u : 0u) | (v[1] > 0.f ? 2u : 0u) |
                   (v[2] > 0.f ? 4u : 0u) | (v[3] > 0.f ? 8u : 0u);
      nib[wid][t * 64 + lane] = (uint8_t)n;
    }
    __syncthreads();
    uint64_t x = *(const uint64_t*)(&nib[wid][8 * lane]);
    uint64_t v = (x | (x >> 4))  & 0x00FF00FF00FF00FFull;
    v          = (v | (v >> 8))  & 0x0000FFFF0000FFFFull;
    v          = (v | (v >> 16));
    mask[(size_t)row * 64 + lane] = (uint32_t)v;
  }

  // ---- k1 body (blocks < 256 only) ----
  if (blockIdx.x < 256) {
    for (int idx = tid; idx < FIN * FOUT; idx += 256) {
      int k = idx >> 6, c = idx & 63;
      wlds[c * 136 + k] = (ushort)(cvt_pk_bf16(W[idx], 0.f) & 0xffffu);
    }
    __syncthreads();

    const int bid = ((blockIdx.x & 7) << 5) | (blockIdx.x >> 3);
    const int q = lane & 15, g = lane >> 4;
    const int wrow0 = bid * 64 + wid * 16;
    const int b  = wrow0 >> 11;
    const int n0 = wrow0 & (NN - 1);

    const float* hrow = h + (size_t)(wrow0 + q) * FIN + 8 * g;

    f32x4 acc[4];
    #pragma unroll
    for (int nt = 0; nt < 4; ++nt) acc[nt] = {0.f, 0.f, 0.f, 0.f};

    #pragma unroll
    for (int kk = 0; kk < 4; ++kk) {
      f32x4 h0 = *(const f32x4*)(hrow + 32 * kk);
      f32x4 h1 = *(const f32x4*)(hrow + 32 * kk + 4);
      s16x8 A = mk_s16x8(cvt_pk_bf16(h0[0], h0[1]), cvt_pk_bf16(h0[2], h0[3]),
                         cvt_pk_bf16(h1[0], h1[1]), cvt_pk_bf16(h1[2], h1[3]));
      #pragma unroll
      for (int nt = 0; nt < 4; ++nt) {
        s16x8 Bf = *(const s16x8*)(&wlds[(nt * 16 + q) * 136 + 32 * kk + 8 * g]);
        acc[nt] = __builtin_amdgcn_mfma_f32_16x16x32_bf16(A, Bf, acc[nt], 0, 0, 0);
      }
    }

    float a1v[4], a2v[4];
    #pragma unroll
    for (int nt = 0; nt < 4; ++nt) {
      a1v[nt] = attw[nt * 16 + q];
      a2v[nt] = attw[64 + nt * 16 + q];
    }
    float p1[4], p2[4];
    #pragma unroll
    for (int r = 0; r < 4; ++r) {
      float v1 = 0.f, v2 = 0.f;
      #pragma unroll
      for (int nt = 0; nt < 4; ++nt) { v1 += acc[nt][r] * a1v[nt]; v2 += acc[nt][r] * a2v[nt]; }
      #pragma unroll
      for (int m = 1; m < 16; m <<= 1) { v1 += __shfl_xor(v1, m, 64); v2 += __shfl_xor(v2, m, 64); }
      p1[r] = v1; p2[r] = v2;
    }
    if (q < 4) {
      int gr = wrow0 + 4 * g + q;
      float v1 = (q == 0) ? p1[0] : (q == 1) ? p1[1] : (q == 2) ? p1[2] : p1[3];
      float v2 = (q == 0) ? p2[0] : (q == 1) ? p2[1] : (q == 2) ? p2[2] : p2[3];
      s1[gr] = v1; s2[gr] = v2;
    }

    #pragma unroll
    for (int nt = 0; nt < 4; ++nt) {
      uint32_t lo = cvt_pk_bf16(acc[nt][0], acc[nt][1]);
      uint32_t hi = cvt_pk_bf16(acc[nt][2], acc[nt][3]);
      *(uint2*)(hidT + ((size_t)b * FOUT + nt * 16 + q) * NN + n0 + 4 * g) = make_uint2(lo, hi);
    }
  }
}

// ---------------------------------------------------------------------------
// k2 v6 (kept from R15, now cleanly A/B'd): GEMM-style + double-buffered
// staging, 1 barrier/chunk.  grid 1024 x 512 thr; block = 64 i x 512 j.
// ---------------------------------------------------------------------------
__global__ void k2_attn(
    const uint32_t* __restrict__ mask, const ushort* __restrict__ hidT,
    const float* __restrict__ s1, const float* __restrict__ s2,
    float* __restrict__ parts) {
  __shared__ __align__(16) char Hb[2][16384];
  __shared__ float s2l[512];
  __shared__ float partl[4][16];

  const int tid = threadIdx.x;
  // XCD swizzle: 1024 blocks, XCD x <- batch x
  const int sb  = ((blockIdx.x & 7) << 7) | (blockIdx.x >> 3);
  const int b   = sb >> 7;
  const int rem = sb & 127;
  const int ib  = rem >> 2;           // i-block 0..31
  const int jq  = rem & 3;            // j-window 0..3
  const int i0  = ib << 6;
  const int jbase = jq << 9;          // 512-j window start

  if (tid < 512) s2l[tid] = s2[b * NN + jbase + tid];

  const int lane = tid & 63, wid = tid >> 6;
  const int q = lane & 15, g = lane >> 4;
  const int r16 = wid & 3;            // row-group
  const int jp  = wid >> 2;           // j-half within chunk
  const int row = i0 + r16 * 16 + q;
  const float s1r = s1[b * NN + row];
  const uint32_t* mrow = mask + (size_t)(b * NN + row) * 64 + jq * 16 + jp * 2;

  const ushort* hsrc = hidT + (size_t)b * FOUT * NN + jbase;
  const int sf = tid >> 4;            // staging f-row 0..31 (+32 second half)
  const int jslot = tid & 15;         // staging 16B slot
  const int swz = (q & 7) << 4;
  const int gsh = g << 3;

  f32x4 acc0 = {0,0,0,0}, acc1 = {0,0,0,0}, acc2 = {0,0,0,0}, acc3 = {0,0,0,0};
  float lsum = 0.f;

  u32x4 v0, v1;
  #define LOADC(cc) do {                                                      \
    const ushort* hp_ = hsrc + (size_t)sf * NN + (cc) * 128 + jslot * 8;      \
    v0 = *(const u32x4*)hp_;                                                  \
    v1 = *(const u32x4*)(hp_ + (size_t)32 * NN);                              \
  } while (0)

  #define DSWC(bb) do {                                                       \
    char* db = Hb[bb];                                                        \
    *(u32x4*)(db + (sf << 8) + ((jslot << 4) ^ ((sf & 7) << 4))) = v0;        \
    *(u32x4*)(db + ((sf + 32) << 8) + ((jslot << 4) ^ ((sf & 7) << 4))) = v1; \
  } while (0)

  // prologue: stage chunk 0
  LOADC(0);
  DSWC(0);
  __syncthreads();

  #pragma unroll
  for (int c = 0; c < 4; ++c) {
    if (c < 3) LOADC(c + 1);           // issue early; lands during compute

    const char* tb = Hb[c & 1];
    #pragma unroll
    for (int s = 0; s < 2; ++s) {
      const int jl = jp * 64 + s * 32 + 8 * g;     // chunk-local 0..127
      const uint32_t mb = (mrow[c * 4 + s] >> gsh) & 0xffu;
      f32x4 ct0 = *(const f32x4*)(s2l + c * 128 + jl);
      f32x4 ct1 = *(const f32x4*)(s2l + c * 128 + jl + 4);
      const int jb = (jl << 1);                    // byte in 256B row
      u32x4 cb0 = *(const u32x4*)(tb + (((0 * 16 + q) << 8) + (jb ^ swz)));
      u32x4 cb1 = *(const u32x4*)(tb + (((1 * 16 + q) << 8) + (jb ^ swz)));
      u32x4 cb2 = *(const u32x4*)(tb + (((2 * 16 + q) << 8) + (jb ^ swz)));
      u32x4 cb3 = *(const u32x4*)(tb + (((3 * 16 + q) << 8) + (jb ^ swz)));

      float e0 = s1r + ct0[0], e1 = s1r + ct0[1], e2 = s1r + ct0[2], e3 = s1r + ct0[3];
      float e4 = s1r + ct1[0], e5 = s1r + ct1[1], e6 = s1r + ct1[2], e7 = s1r + ct1[3];
      float p0 = (mb &   1u) ? __expf(fmaxf(e0, 0.2f * e0)) : 0.f;
      float p1 = (mb &   2u) ? __expf(fmaxf(e1, 0.2f * e1)) : 0.f;
      float p2 = (mb &   4u) ? __expf(fmaxf(e2, 0.2f * e2)) : 0.f;
      float p3 = (mb &   8u) ? __expf(fmaxf(e3, 0.2f * e3)) : 0.f;
      float p4 = (mb &  16u) ? __expf(fmaxf(e4, 0.2f * e4)) : 0.f;
      float p5 = (mb &  32u) ? __expf(fmaxf(e5, 0.2f * e5)) : 0.f;
      float p6 = (mb &  64u) ? __expf(fmaxf(e6, 0.2f * e6)) : 0.f;
      float p7 = (mb & 128u) ? __expf(fmaxf(e7, 0.2f * e7)) : 0.f;
      lsum += ((p0 + p1) + (p2 + p3)) + ((p4 + p5) + (p6 + p7));

      s16x8 A = mk_s16x8(cvt_pk_bf16(p0, p1), cvt_pk_bf16(p2, p3),
                         cvt_pk_bf16(p4, p5), cvt_pk_bf16(p6, p7));
      union { u32x4 u; s16x8 v; } w0, w1, w2, w3;
      w0.u = cb0; w1.u = cb1; w2.u = cb2; w3.u = cb3;
      acc0 = __builtin_amdgcn_mfma_f32_16x16x32_bf16(A, w0.v, acc0, 0, 0, 0);
      acc1 = __builtin_amdgcn_mfma_f32_16x16x32_bf16(A, w1.v, acc1, 0, 0, 0);
      acc2 = __builtin_amdgcn_mfma_f32_16x16x32_bf16(A, w2.v, acc2, 0, 0, 0);
      acc3 = __builtin_amdgcn_mfma_f32_16x16x32_bf16(A, w3.v, acc3, 0, 0, 0);
    }

    if (c < 3) DSWC((c + 1) & 1);      // write-late into the other buffer
    __syncthreads();
  }

  // reduce lsum over g-groups -> all lanes hold row-q sum (this wave's j-part)
  lsum += __shfl_xor(lsum, 16, 64);
  lsum += __shfl_xor(lsum, 32, 64);

  // combine j-half pairs (wid and wid+4 share rows); part aliases Hb[0]
  float* part = (float*)Hb[0];   // [4][16][64]
  if (wid >= 4) {
    if (lane < 16) partl[wid - 4][lane] = lsum;
    #pragma unroll
    for (int r = 0; r < 4; ++r) {
      part[((wid - 4) * 16 + 4 * g + r) * 64 +  0 + q] = acc0[r];
      part[((wid - 4) * 16 + 4 * g + r) * 64 + 16 + q] = acc1[r];
      part[((wid - 4) * 16 + 4 * g + r) * 64 + 32 + q] = acc2[r];
      part[((wid - 4) * 16 + 4 * g + r) * 64 + 48 + q] = acc3[r];
    }
  }
  __syncthreads();
  if (wid < 4) {
    lsum += partl[wid][q];
    #pragma unroll
    for (int r = 0; r < 4; ++r) {
      acc0[r] += part[(wid * 16 + 4 * g + r) * 64 +  0 + q];
      acc1[r] += part[(wid * 16 + 4 * g + r) * 64 + 16 + q];
      acc2[r] += part[(wid * 16 + 4 * g + r) * 64 + 32 + q];
      acc3[r] += part[(wid * 16 + 4 * g + r) * 64 + 48 + q];
    }
    float* po = parts + ((size_t)(b * 32 + ib) * 4 + jq) * 4160;
    #pragma unroll
    for (int r = 0; r < 4; ++r) {
      po[(r16 * 16 + 4 * g + r) * 64 +  0 + q] = acc0[r];
      po[(r16 * 16 + 4 * g + r) * 64 + 16 + q] = acc1[r];
      po[(r16 * 16 + 4 * g + r) * 64 + 32 + q] = acc2[r];
      po[(r16 * 16 + 4 * g + r) * 64 + 48 + q] = acc3[r];
    }
    if (lane < 16) po[4096 + r16 * 16 + q] = lsum;
  }
}

// ---------------------------------------------------------------------------
// k3: combine 4 j-window partials, normalize, ELU, write out.
// ---------------------------------------------------------------------------
__global__ void k3_combine(const float* __restrict__ parts, float* __restrict__ out) {
  __shared__ float lrow[64];
  const int tid = threadIdx.x;
  const int sb  = ((blockIdx.x & 7) << 5) | (blockIdx.x >> 3);
  const int b   = sb >> 5;
  const int ib  = sb & 31;
  const float* p0 = parts + (size_t)(b * 32 + ib) * 4 * 4160;

  if (tid < 64)
    lrow[tid] = (p0[4096 + tid] + p0[4160 + 4096 + tid]) +
                (p0[8320 + 4096 + tid] + p0[12480 + 4096 + tid]);
  __syncthreads();

  #pragma unroll
  for (int k = 0; k < 16; ++k) {
    const int idx = k * 256 + tid;
    const int row = idx >> 6, col = idx & 63;
    float v = (p0[idx] + p0[4160 + idx]) + (p0[8320 + idx] + p0[12480 + idx]);
    float hp = v / lrow[row];
    out[(size_t)(b * NN + ib * 64 + row) * 64 + col] = (hp > 0.f) ? hp : expm1f(hp);
  }
}

extern "C" void kernel_launch(void* const* d_in, const int* in_sizes, int n_in,
                              void* d_out, int out_size, void* d_ws, size_t ws_size,
                              hipStream_t stream) {
  const float* h    = (const float*)d_in[0];
  const float* adj  = (const float*)d_in[1];
  const float* W    = (const float*)d_in[2];
  const float* attw = (const float*)d_in[3];
  float* out = (float*)d_out;

  char* ws = (char*)d_ws;
  ushort*   hidT  = (ushort*)ws;                                // 2 MB
  float*    s1    = (float*)(ws + (2u << 20));                  // 64 KB
  float*    s2    = (float*)(ws + (2u << 20) + (64u << 10));    // 64 KB
  uint32_t* mask  = (uint32_t*)(ws + (4u << 20));               // 4 MB
  float*    parts = (float*)(ws + (8u << 20));                  // 17 MB

  hipLaunchKernelGGL(k01, dim3(4096), dim3(256), 0, stream,
                     adj, mask, h, W, attw, hidT, s1, s2);
  hipLaunchKernelGGL(k2_attn, dim3(1024), dim3(512), 0, stream,
                     mask, hidT, s1, s2, parts);
  hipLaunchKernelGGL(k3_combine, dim3(256), dim3(256), 0, stream, parts, out);
}

// Round 17
// 41.954 us; speedup vs baseline: 2.0220x; 1.4275x over previous
//
#include <hip/hip_runtime.h>
#include <stdint.h>

typedef float f32x4 __attribute__((ext_vector_type(4)));
typedef uint32_t u32x4 __attribute__((ext_vector_type(4)));
typedef short s16x8 __attribute__((ext_vector_type(8)));

#define BB   8
#define NN   2048
#define FIN  128
#define FOUT 64

__device__ __forceinline__ uint32_t cvt_pk_bf16(float lo, float hi) {
  uint32_t r;
  asm("v_cvt_pk_bf16_f32 %0, %1, %2" : "=v"(r) : "v"(lo), "v"(hi));
  return r;
}

__device__ __forceinline__ s16x8 mk_s16x8(uint32_t a, uint32_t b, uint32_t c, uint32_t d) {
  union { uint32_t u[4]; s16x8 v; } x;
  x.u[0] = a; x.u[1] = b; x.u[2] = c; x.u[3] = d;
  return x.v;
}

// ---------------------------------------------------------------------------
// Kernel 1 (R1 lineage, proven): hidden = h @ W -> hidT [b][f][n] bf16; s1,s2.
// ---------------------------------------------------------------------------
__global__ void k1_hidden(const float* __restrict__ h, const float* __restrict__ W,
                          const float* __restrict__ attw, ushort* __restrict__ hidT,
                          float* __restrict__ s1, float* __restrict__ s2) {
  __shared__ ushort wlds[FOUT * 136];
  const int tid = threadIdx.x;

  for (int idx = tid; idx < FIN * FOUT; idx += 256) {
    int k = idx >> 6, c = idx & 63;
    wlds[c * 136 + k] = (ushort)(cvt_pk_bf16(W[idx], 0.f) & 0xffffu);
  }
  __syncthreads();

  const int bid = ((blockIdx.x & 7) << 5) | (blockIdx.x >> 3);
  const int lane = tid & 63, wid = tid >> 6;
  const int q = lane & 15, g = lane >> 4;
  const int wrow0 = bid * 64 + wid * 16;
  const int b  = wrow0 >> 11;
  const int n0 = wrow0 & (NN - 1);

  const float* hrow = h + (size_t)(wrow0 + q) * FIN + 8 * g;

  f32x4 acc[4];
  #pragma unroll
  for (int nt = 0; nt < 4; ++nt) acc[nt] = {0.f, 0.f, 0.f, 0.f};

  #pragma unroll
  for (int kk = 0; kk < 4; ++kk) {
    f32x4 h0 = *(const f32x4*)(hrow + 32 * kk);
    f32x4 h1 = *(const f32x4*)(hrow + 32 * kk + 4);
    s16x8 A = mk_s16x8(cvt_pk_bf16(h0[0], h0[1]), cvt_pk_bf16(h0[2], h0[3]),
                       cvt_pk_bf16(h1[0], h1[1]), cvt_pk_bf16(h1[2], h1[3]));
    #pragma unroll
    for (int nt = 0; nt < 4; ++nt) {
      s16x8 Bf = *(const s16x8*)(&wlds[(nt * 16 + q) * 136 + 32 * kk + 8 * g]);
      acc[nt] = __builtin_amdgcn_mfma_f32_16x16x32_bf16(A, Bf, acc[nt], 0, 0, 0);
    }
  }

  float a1v[4], a2v[4];
  #pragma unroll
  for (int nt = 0; nt < 4; ++nt) {
    a1v[nt] = attw[nt * 16 + q];
    a2v[nt] = attw[64 + nt * 16 + q];
  }
  float p1[4], p2[4];
  #pragma unroll
  for (int r = 0; r < 4; ++r) {
    float v1 = 0.f, v2 = 0.f;
    #pragma unroll
    for (int nt = 0; nt < 4; ++nt) { v1 += acc[nt][r] * a1v[nt]; v2 += acc[nt][r] * a2v[nt]; }
    #pragma unroll
    for (int m = 1; m < 16; m <<= 1) { v1 += __shfl_xor(v1, m, 64); v2 += __shfl_xor(v2, m, 64); }
    p1[r] = v1; p2[r] = v2;
  }
  if (q < 4) {
    int gr = wrow0 + 4 * g + q;
    float v1 = (q == 0) ? p1[0] : (q == 1) ? p1[1] : (q == 2) ? p1[2] : p1[3];
    float v2 = (q == 0) ? p2[0] : (q == 1) ? p2[1] : (q == 2) ? p2[2] : p2[3];
    s1[gr] = v1; s2[gr] = v2;
  }

  #pragma unroll
  for (int nt = 0; nt < 4; ++nt) {
    uint32_t lo = cvt_pk_bf16(acc[nt][0], acc[nt][1]);
    uint32_t hi = cvt_pk_bf16(acc[nt][2], acc[nt][3]);
    *(uint2*)(hidT + ((size_t)b * FOUT + nt * 16 + q) * NN + n0 + 4 * g) = make_uint2(lo, hi);
  }
}

// ---------------------------------------------------------------------------
// kF: FUSED adj-stream + softmax + PV.  grid 512 x 512 thr (2 blocks/CU by
// LDS).  Block = 32 i-rows x 2048 j, 8 chunks of 256 j.  Per chunk: adj
// (HBM, reg-staged early = T14) and hidden (L2-hot, reg-staged) -> LDS with
// XOR swizzle; compute 2 k-steps/wave (waves = 2 row-groups x 4 j-quarters).
// Complete output rows in-block: no mask kernel, no parts, no k3.
// LDS: adjL[32][256]f32 32KB | HL[64][256]bf16 32KB | s2l 8KB | partl 0.5KB.
// part[4][32][64] (epilogue) aliases adjL.
// ---------------------------------------------------------------------------
__global__ __launch_bounds__(512, 4) void kF(
    const float* __restrict__ adj, const ushort* __restrict__ hidT,
    const float* __restrict__ s1g, const float* __restrict__ s2g,
    float* __restrict__ out) {
  __shared__ __align__(16) char smem[74240];
  float* s2l   = (float*)(smem + 65536);
  float* partl = (float*)(smem + 73728);

  const int tid = threadIdx.x;
  // XCD swizzle: 512 blocks, XCD x <- 64 contiguous = batch x
  const int sb = ((blockIdx.x & 7) << 6) | (blockIdx.x >> 3);
  const int b  = sb >> 6;
  const int i0 = (sb & 63) << 5;

  const int lane = tid & 63, wid = tid >> 6;
  const int q = lane & 15, g = lane >> 4;
  const int rg = wid >> 2, jw = wid & 3;

  // s2 stage (once, 8KB)
  *(f32x4*)(s2l + tid * 4) = *(const f32x4*)(s2g + b * NN + tid * 4);
  const float s1r = s1g[b * NN + i0 + rg * 16 + q];

  // staging bases: adj = 1KB-contiguous per wave-instr (wid const per wave)
  const float* adjB = adj + ((size_t)(b * NN + i0 + wid)) * NN + lane * 4;
  const int f0 = tid >> 5, sl = tid & 31;
  const ushort* hBp = hidT + ((size_t)(b * FOUT + f0)) * NN + sl * 8;
  const int aswz = (lane << 4), awx = (wid & 7) << 4;
  const int hswz = (sl << 4) ^ ((f0 & 7) << 4);

  f32x4 aA, aB, aC, aD; u32x4 hA, hB, hC, hD;

#define ADJ_LOAD(cc) do {                                                     \
    const float* p_ = adjB + (cc) * 256;                                      \
    aA = *(const f32x4*)(p_);                                                 \
    aB = *(const f32x4*)(p_ + (size_t) 8 * NN);                               \
    aC = *(const f32x4*)(p_ + (size_t)16 * NN);                               \
    aD = *(const f32x4*)(p_ + (size_t)24 * NN);                               \
  } while (0)

#define ADJ_WRITE() do {                                                      \
    *(f32x4*)(smem + (wid     ) * 1024 + (aswz ^ awx)) = aA;                  \
    *(f32x4*)(smem + (wid +  8) * 1024 + (aswz ^ awx)) = aB;                  \
    *(f32x4*)(smem + (wid + 16) * 1024 + (aswz ^ awx)) = aC;                  \
    *(f32x4*)(smem + (wid + 24) * 1024 + (aswz ^ awx)) = aD;                  \
  } while (0)

#define H_LOAD(cc) do {                                                       \
    const ushort* p_ = hBp + (cc) * 256;                                      \
    hA = *(const u32x4*)(p_);                                                 \
    hB = *(const u32x4*)(p_ + (size_t)16 * NN);                               \
    hC = *(const u32x4*)(p_ + (size_t)32 * NN);                               \
    hD = *(const u32x4*)(p_ + (size_t)48 * NN);                               \
  } while (0)

#define H_WRITE() do {                                                        \
    char* d_ = smem + 32768;                                                  \
    *(u32x4*)(d_ + (f0     ) * 512 + hswz) = hA;                              \
    *(u32x4*)(d_ + (f0 + 16) * 512 + hswz) = hB;                              \
    *(u32x4*)(d_ + (f0 + 32) * 512 + hswz) = hC;                              \
    *(u32x4*)(d_ + (f0 + 48) * 512 + hswz) = hD;                              \
  } while (0)

  // prologue: stage chunk 0
  ADJ_LOAD(0); H_LOAD(0);
  ADJ_WRITE(); H_WRITE();

  f32x4 acc0 = {0,0,0,0}, acc1 = {0,0,0,0}, acc2 = {0,0,0,0}, acc3 = {0,0,0,0};
  float lsum = 0.f;
  const int xr = (q & 7) << 4;
  const int arow = (rg * 16 + q) * 1024;

  #pragma unroll
  for (int c = 0; c < 8; ++c) {
    __syncthreads();                         // stage(c) visible
    if (c < 7) { ADJ_LOAD(c + 1); H_LOAD(c + 1); }   // HBM/L2 issue early

    #pragma unroll
    for (int s = 0; s < 2; ++s) {
      const int joff = jw * 256 + s * 128 + g * 32;          // adjL byte base
      f32x4 av0 = *(const f32x4*)(smem + arow + ((joff     ) ^ xr));
      f32x4 av1 = *(const f32x4*)(smem + arow + ((joff + 16) ^ xr));
      const int jl = jw * 64 + s * 32 + 8 * g;
      f32x4 t0 = *(const f32x4*)(s2l + c * 256 + jl);
      f32x4 t1 = *(const f32x4*)(s2l + c * 256 + jl + 4);
      const int hoff = (jw * 128 + s * 64 + g * 16) ^ xr;
      const char* hL = smem + 32768;
      u32x4 b0 = *(const u32x4*)(hL + (( 0 + q) << 9) + hoff);
      u32x4 b1 = *(const u32x4*)(hL + ((16 + q) << 9) + hoff);
      u32x4 b2 = *(const u32x4*)(hL + ((32 + q) << 9) + hoff);
      u32x4 b3 = *(const u32x4*)(hL + ((48 + q) << 9) + hoff);

      // p = adj * exp(leakyrelu(s1+s2));  adj is exactly 0 or 1
      float e0 = s1r + t0[0], e1 = s1r + t0[1], e2 = s1r + t0[2], e3 = s1r + t0[3];
      float e4 = s1r + t1[0], e5 = s1r + t1[1], e6 = s1r + t1[2], e7 = s1r + t1[3];
      float p0 = av0[0] * __expf(fmaxf(e0, 0.2f * e0));
      float p1 = av0[1] * __expf(fmaxf(e1, 0.2f * e1));
      float p2 = av0[2] * __expf(fmaxf(e2, 0.2f * e2));
      float p3 = av0[3] * __expf(fmaxf(e3, 0.2f * e3));
      float p4 = av1[0] * __expf(fmaxf(e4, 0.2f * e4));
      float p5 = av1[1] * __expf(fmaxf(e5, 0.2f * e5));
      float p6 = av1[2] * __expf(fmaxf(e6, 0.2f * e6));
      float p7 = av1[3] * __expf(fmaxf(e7, 0.2f * e7));
      lsum += ((p0 + p1) + (p2 + p3)) + ((p4 + p5) + (p6 + p7));

      s16x8 A = mk_s16x8(cvt_pk_bf16(p0, p1), cvt_pk_bf16(p2, p3),
                         cvt_pk_bf16(p4, p5), cvt_pk_bf16(p6, p7));
      union { u32x4 u; s16x8 v; } w0, w1, w2, w3;
      w0.u = b0; w1.u = b1; w2.u = b2; w3.u = b3;
      acc0 = __builtin_amdgcn_mfma_f32_16x16x32_bf16(A, w0.v, acc0, 0, 0, 0);
      acc1 = __builtin_amdgcn_mfma_f32_16x16x32_bf16(A, w1.v, acc1, 0, 0, 0);
      acc2 = __builtin_amdgcn_mfma_f32_16x16x32_bf16(A, w2.v, acc2, 0, 0, 0);
      acc3 = __builtin_amdgcn_mfma_f32_16x16x32_bf16(A, w3.v, acc3, 0, 0, 0);
    }

    __syncthreads();                         // reads of chunk c done
    if (c < 7) { ADJ_WRITE(); H_WRITE(); }   // write-late into LDS
  }

  // lsum: combine g-groups (same row q)
  lsum += __shfl_xor(lsum, 16, 64);
  lsum += __shfl_xor(lsum, 32, 64);
  if (lane < 16) partl[jw * 32 + rg * 16 + lane] = lsum;

  // per-wave partials -> part (aliases adjL; last barrier above protects it)
  float* part = (float*)smem;   // [4 jw][32 row][64 col]
  #pragma unroll
  for (int r = 0; r < 4; ++r) {
    const int il = rg * 16 + 4 * g + r;
    part[(jw * 32 + il) * 64 +  0 + q] = acc0[r];
    part[(jw * 32 + il) * 64 + 16 + q] = acc1[r];
    part[(jw * 32 + il) * 64 + 32 + q] = acc2[r];
    part[(jw * 32 + il) * 64 + 48 + q] = acc3[r];
  }
  __syncthreads();

  // combine 4 j-quarters, normalize, ELU, write 32x64 outputs
  #pragma unroll
  for (int k = 0; k < 4; ++k) {
    const int idx = tid + 512 * k;
    const int row = idx >> 6, col = idx & 63;
    float v  = (part[(0 * 32 + row) * 64 + col] + part[(1 * 32 + row) * 64 + col]) +
               (part[(2 * 32 + row) * 64 + col] + part[(3 * 32 + row) * 64 + col]);
    float li = (partl[0 * 32 + row] + partl[1 * 32 + row]) +
               (partl[2 * 32 + row] + partl[3 * 32 + row]);
    float hp = v / li;
    out[(size_t)(b * NN + i0 + row) * 64 + col] = (hp > 0.f) ? hp : expm1f(hp);
  }
}

extern "C" void kernel_launch(void* const* d_in, const int* in_sizes, int n_in,
                              void* d_out, int out_size, void* d_ws, size_t ws_size,
                              hipStream_t stream) {
  const float* h    = (const float*)d_in[0];
  const float* adj  = (const float*)d_in[1];
  const float* W    = (const float*)d_in[2];
  const float* attw = (const float*)d_in[3];
  float* out = (float*)d_out;

  char* ws = (char*)d_ws;
  ushort* hidT = (ushort*)ws;                                   // 2 MB
  float*  s1   = (float*)(ws + (2u << 20));                     // 64 KB
  float*  s2   = (float*)(ws + (2u << 20) + (64u << 10));       // 64 KB

  hipLaunchKernelGGL(k1_hidden, dim3(256), dim3(256), 0, stream, h, W, attw, hidT, s1, s2);
  hipLaunchKernelGGL(kF, dim3(512), dim3(512), 0, stream, adj, hidT, s1, s2, out);
}